// Round 9
// baseline (48779.581 us; speedup 1.0000x reference)
//
#include <hip/hip_runtime.h>
#include <cmath>

#define LN 256
#define MM 8
#define HIDN 1024
#define NSTEP 2047
#define NWG 32
#define TPB 256
#define W1R 32      // W1 rows per WG (HID/NWG)
#define GR 8        // state rows per WG (L/NWG)
#define ZUN (LN+MM) // 264

#define KAPPA 0.65f
#define GAMMA 0.41f
#define TAUC 0.98f
#define INV_HALPHA 3.125f
#define RHOC 0.34f
#define V0C 0.04f
#define ALPHA 0.1f
#define LOG2_1MRHO (-0.5994620717f)

#define DEADMAN (1<<14)  // poll spin cap: a bug becomes a finishing failing run

// ---- LDS layout (floats) ----
#define OFF_W1 0
#define N_W1 (W1R*ZUN)            // 8448
#define OFF_W2 (OFF_W1+N_W1)
#define N_W2 (W1R*LN)             // 8192 (transposed own-column slice: [c][r])
#define OFF_A (OFF_W2+N_W2)
#define N_A (GR*LN)               // 2048
#define OFF_B (OFF_A+N_A)
#define N_B (MM*GR*LN)            // 16384
#define OFF_C (OFF_B+N_B)
#define N_C (GR*MM)               // 64
#define OFF_B1 (OFF_C+N_C)
#define N_B1 (W1R)                // 32
#define OFF_B2 (OFF_B1+N_B1)
#define N_B2 (GR)                 // 8
#define OFF_ZA (OFF_B2+N_B2)      // 35176
#define OFF_ZB (OFF_ZA+ZUN)       // 35440
#define OFF_H (OFF_ZB+ZUN)        // 35704
#define OFF_P (OFF_H+W1R)         // 35736
#define SMEM_FLOATS (OFF_P+GR)    // 35744
#define SMEM_BYTES (SMEM_FLOATS*4) // 142976 <= 163840

// d_ws layout:
//   flags[4][NWG] u32  (4 x 128B lines; flags[w][g] = last stage+1 whose wave-w
//                       partials from WG g are at the coherence point)
//   part[2][NWG][LN] floats at byte 1024 (64 KB), parity ping-pong
#define WS_PART_OFF 1024

__global__ void dcm_init(unsigned* flags) {
  if (threadIdx.x < 4 * NWG) flags[threadIdx.x] = 0u;   // monotonic epochs restart each launch
}

__global__ void __launch_bounds__(TPB, 1) dcm_kernel(
    const float* __restrict__ Ag, const float* __restrict__ Bg,
    const float* __restrict__ Cg, const float* __restrict__ W1g,
    const float* __restrict__ b1g, const float* __restrict__ W2g,
    const float* __restrict__ b2g, const float* __restrict__ Ug,
    const float* __restrict__ Tg, float* __restrict__ outg,
    float* __restrict__ part, unsigned* __restrict__ flags)
{
  extern __shared__ float sm[];
  const int wg = blockIdx.x, tid = threadIdx.x;
  const int myw = tid >> 6;                 // wave slot (0..3)
  float* w1s = sm + OFF_W1;
  float* w2s = sm + OFF_W2;
  float* as_ = sm + OFF_A;
  float* bs_ = sm + OFF_B;
  float* cs_ = sm + OFF_C;
  float* b1s = sm + OFF_B1;
  float* b2s = sm + OFF_B2;
  float* zA  = sm + OFF_ZA;
  float* zB  = sm + OFF_ZB;
  float* hsh = sm + OFF_H;
  float* pts = sm + OFF_P;

  // ---- stage weights into LDS (once) ----
  for (int i = tid; i < N_W1; i += TPB) {
    int r = i / ZUN, k = i - r * ZUN;
    w1s[i] = W1g[(wg * W1R + r) * ZUN + k];
  }
  for (int i = tid; i < N_W2; i += TPB) {
    int c = i >> 8, r = i & (LN - 1);
    w2s[i] = W2g[r * HIDN + wg * W1R + c];   // transposed: w2s[c][r]
  }
  for (int i = tid; i < N_A; i += TPB) {
    int r = i >> 8, k = i & (LN - 1);
    as_[i] = Ag[(wg * GR + r) * LN + k];
  }
  for (int i = tid; i < N_B; i += TPB) {
    int m = i / (GR * LN); int rem = i - m * GR * LN;
    int r = rem >> 8, k = rem & (LN - 1);
    bs_[i] = Bg[(m * LN + wg * GR + r) * LN + k];
  }
  for (int i = tid; i < N_C; i += TPB) {
    int r = i >> 3, m = i & 7;
    cs_[i] = Cg[(wg * GR + r) * MM + m];
  }
  for (int i = tid; i < N_B1; i += TPB) b1s[i] = b1g[wg * W1R + i];
  for (int i = tid; i < N_B2; i += TPB) b2s[i] = b2g[wg * GR + i];

  float zb = 0.f, sb = 0.f, fb = 1.f, vb = 1.f, qb = 1.f;
  zA[tid] = 0.f;                            // initial z (stage-0 buffer)

  if (wg == 0) {                            // output row 0
    outg[tid] = 0.f;
    outg[LN + tid] = 0.f;
    outg[2 * LN + tid] = 1.f;
    outg[3 * LN + tid] = 1.f;
    outg[4 * LN + tid] = 1.f;
    outg[(size_t)2048 * 1280 + tid] = 0.f;
  }

  for (int t = 0; t < NSTEP; ++t) {
    float hstep = Tg[t + 1] - Tg[t];
    float zst = zb, sst = sb, fst = fb, vst = vb, qst = qb;
    float kz = 0.f, ks = 0.f, kf = 0.f, kv = 0.f, kq = 0.f;

    float u0r = 0.f, umr = 0.f, u1r = 0.f;
    if (tid < MM) {
      u0r = Ug[(2 * t) * MM + tid];
      umr = Ug[(2 * t + 1) * MM + tid];
      u1r = Ug[(2 * t + 2) * MM + tid];
    }

    for (int st = 0; st < 4; ++st) {
      const int stg = 4 * t + st;
      const unsigned fl = (unsigned)stg + 1;
      float* zcur = (st & 1) ? zB : zA;
      float* znxt = (st & 1) ? zA : zB;
      float* pslot = part + (size_t)(stg & 1) * (NWG * LN);

      if (tid < MM) zcur[LN + tid] = (st == 0) ? u0r : (st == 3) ? u1r : umr;
      __syncthreads();                      // (a) z (prev stage) + u visible

      float uu[MM];
      #pragma unroll
      for (int m = 0; m < MM; ++m) uu[m] = zcur[LN + m];

      // ---- phase 1: own 32 h rows = tanh(W1 @ zu + b1) ----
      {
        int row = tid >> 3, sub = tid & 7;
        const float* wrow = w1s + row * ZUN + sub * 33;
        const float* zrow = zcur + sub * 33;
        float acc = 0.f;
        #pragma unroll
        for (int j = 0; j < 33; ++j) acc += wrow[j] * zrow[j];
        acc += __shfl_xor(acc, 1);
        acc += __shfl_xor(acc, 2);
        acc += __shfl_xor(acc, 4);
        if (sub == 0) hsh[row] = tanhf(acc + b1s[row]);
      }
      // ---- phase 2: own 8 rows of (A + sum u_m B_m) z + Cu + alpha b2 ----
      {
        int grow = tid >> 5, gsub = tid & 31;
        const float* arow = as_ + grow * LN;
        float ga = 0.f;
        #pragma unroll
        for (int j = 0; j < 8; ++j) {
          int k = gsub + 32 * j;
          float w = arow[k];
          #pragma unroll
          for (int m = 0; m < MM; ++m) w += uu[m] * bs_[(m * GR + grow) * LN + k];
          ga += w * zcur[k];
        }
        ga += __shfl_xor(ga, 1);
        ga += __shfl_xor(ga, 2);
        ga += __shfl_xor(ga, 4);
        ga += __shfl_xor(ga, 8);
        ga += __shfl_xor(ga, 16);
        if (gsub == 0) {
          float cu = 0.f;
          #pragma unroll
          for (int m = 0; m < MM; ++m) cu += cs_[grow * MM + m] * uu[m];
          pts[grow] = ga + cu + ALPHA * b2s[grow];
        }
      }
      __syncthreads();                      // (b) hsh, pts visible

      // ---- phase 3: column-partial of alpha*W2@h + own exact rows; store ----
      {
        float a2 = 0.f;
        #pragma unroll 8
        for (int c = 0; c < W1R; ++c) a2 += w2s[c * LN + tid] * hsh[c];
        float pr = ALPHA * a2;
        int rl = tid - wg * GR;
        if (rl >= 0 && rl < GR) pr += pts[rl];
        __hip_atomic_store(&pslot[wg * LN + tid], pr,
                           __ATOMIC_RELAXED, __HIP_MEMORY_SCOPE_AGENT);
      }

      // ---- hemodynamic elementwise (regs only; hides partial-store flight) ----
      float ds = zst - KAPPA * sst - GAMMA * (fst - 1.f);
      float df = sst;
      float fv = exp2f(INV_HALPHA * log2f(vst));
      float dv = (fst - fv) / TAUC;
      float E  = 1.f - exp2f(LOG2_1MRHO / fst);
      float dq = (fst * E / RHOC - fv * qst / vst) / TAUC;

      // ---- drain THIS wave's store to the coherence point, then flag ----
      asm volatile("s_waitcnt vmcnt(0)" ::: "memory");
      if ((tid & 63) == 0)
        __hip_atomic_store(&flags[myw * NWG + wg], fl,
                           __ATOMIC_RELAXED, __HIP_MEMORY_SCOPE_AGENT);

      // ---- poll my wave-slot's flag line (ONE 128B segment per round) ----
      {
        const unsigned* fp_ = &flags[myw * NWG + (tid & 31)];
        int spins = 0;
        for (;;) {
          unsigned v = __hip_atomic_load(fp_, __ATOMIC_RELAXED,
                                         __HIP_MEMORY_SCOPE_AGENT);
          if (__ballot(v >= fl) == 0xFFFFFFFFFFFFFFFFull) break;
          if (++spins > DEADMAN) break;     // never in theory
        }
      }

      // ---- wide gather: issue all 32 loads, then ordered sum ----
      float arr[NWG];
      #pragma unroll
      for (int g = 0; g < NWG; ++g)
        arr[g] = __hip_atomic_load(&pslot[g * LN + tid],
                                   __ATOMIC_RELAXED, __HIP_MEMORY_SCOPE_AGENT);
      float dz = 0.f;
      #pragma unroll
      for (int g = 0; g < NWG; ++g) dz += arr[g];

      float wk = (st == 0 || st == 3) ? 1.f : 2.f;
      kz += wk * dz; ks += wk * ds; kf += wk * df; kv += wk * dv; kq += wk * dq;

      if (st < 3) {
        float c = (st == 2) ? hstep : 0.5f * hstep;
        zst = zb + c * dz; sst = sb + c * ds; fst = fb + c * df;
        vst = vb + c * dv; qst = qb + c * dq;
        znxt[tid] = zst;                    // other buffer: no reader conflict
      }
    }

    float h6 = hstep * (1.f / 6.f);
    zb += h6 * kz; sb += h6 * ks; fb += h6 * kf; vb += h6 * kv; qb += h6 * kq;
    zA[tid] = zb;                           // next step's stage-0 buffer

    if ((t & (NWG - 1)) == wg) {            // distribute output writes
      size_t ro = (size_t)(t + 1) * 1280;
      outg[ro + tid] = zb;
      outg[ro + LN + tid] = sb;
      outg[ro + 2 * LN + tid] = fb;
      outg[ro + 3 * LN + tid] = vb;
      outg[ro + 4 * LN + tid] = qb;
      float yv = V0C * (2.38f * (1.f - qb) + 2.f * (1.f - qb / vb) + 0.48f * (1.f - vb));
      outg[(size_t)2048 * 1280 + (size_t)(t + 1) * LN + tid] = yv;
    }
  }
}

extern "C" void kernel_launch(void* const* d_in, const int* in_sizes, int n_in,
                              void* d_out, int out_size, void* d_ws, size_t ws_size,
                              hipStream_t stream) {
  const float* Ag  = (const float*)d_in[0];
  const float* Bg  = (const float*)d_in[1];
  const float* Cg  = (const float*)d_in[2];
  const float* W1g = (const float*)d_in[3];
  const float* b1g = (const float*)d_in[4];
  const float* W2g = (const float*)d_in[5];
  const float* b2g = (const float*)d_in[6];
  const float* Ug  = (const float*)d_in[7];
  const float* Tg  = (const float*)d_in[8];
  float* outg = (float*)d_out;

  unsigned* flags = (unsigned*)d_ws;
  float* part = (float*)((char*)d_ws + WS_PART_OFF);

  hipFuncSetAttribute((const void*)dcm_kernel,
                      hipFuncAttributeMaxDynamicSharedMemorySize, SMEM_BYTES);

  hipLaunchKernelGGL(dcm_init, dim3(1), dim3(256), 0, stream, flags);
  hipLaunchKernelGGL(dcm_kernel, dim3(NWG), dim3(TPB), SMEM_BYTES, stream,
                     Ag, Bg, Cg, W1g, b1g, W2g, b2g, Ug, Tg, outg, part, flags);
}

// Round 10
// 47255.475 us; speedup vs baseline: 1.0323x; 1.0323x over previous
//
#include <hip/hip_runtime.h>
#include <cmath>

#define LN 256
#define MM 8
#define HIDN 1024
#define NSTEP 2047
#define NWG 32
#define TPB 256
#define W1R 32      // W1 rows per WG (HID/NWG)
#define GR 8        // state rows per WG (L/NWG)
#define ZUN (LN+MM) // 264

#define KAPPA 0.65f
#define GAMMA 0.41f
#define TAUC 0.98f
#define INV_HALPHA 3.125f
#define RHOC 0.34f
#define V0C 0.04f
#define ALPHA 0.1f
#define LOG2_1MRHO (-0.5994620717f)

#define DEADMAN (1<<13)  // poll-round cap: a protocol bug finishes (failing) instead of hanging

typedef unsigned long long u64;

// ---- LDS layout (floats) ----
#define OFF_W1 0
#define N_W1 (W1R*ZUN)            // 8448
#define OFF_W2 (OFF_W1+N_W1)
#define N_W2 (W1R*LN)             // 8192 (transposed own-column slice: [c][r])
#define OFF_A (OFF_W2+N_W2)
#define N_A (GR*LN)               // 2048
#define OFF_B (OFF_A+N_A)
#define N_B (MM*GR*LN)            // 16384
#define OFF_C (OFF_B+N_B)
#define N_C (GR*MM)               // 64
#define OFF_B1 (OFF_C+N_C)
#define N_B1 (W1R)                // 32
#define OFF_B2 (OFF_B1+N_B1)
#define N_B2 (GR)                 // 8
#define OFF_ZA (OFF_B2+N_B2)      // 35176
#define OFF_ZB (OFF_ZA+ZUN)       // 35440
#define OFF_H (OFF_ZB+ZUN)        // 35704
#define OFF_P (OFF_H+W1R)         // 35736
#define SMEM_FLOATS (OFF_P+GR)    // 35744
#define SMEM_BYTES (SMEM_FLOATS*4) // 142976 <= 163840

// d_ws: ex[2][NWG][LN] u64 (fused epoch<<32 | f32bits), 128 KB, parity ping-pong.
// NO INIT NEEDED: expected epochs are 1..8188; 0xAA poison and cross-replay
// leftovers (epochs 8187/8188 in their final slots) can never equal the epoch
// being polled before the slot's first fresh write (lag argument: a producer
// reaches stage n+2 only after every WG consumed stage n).

__device__ __forceinline__ u64 fuse(unsigned e, float x) {
  return ((u64)e << 32) | (u64)__float_as_uint(x);
}

__global__ void __launch_bounds__(TPB, 1) dcm_kernel(
    const float* __restrict__ Ag, const float* __restrict__ Bg,
    const float* __restrict__ Cg, const float* __restrict__ W1g,
    const float* __restrict__ b1g, const float* __restrict__ W2g,
    const float* __restrict__ b2g, const float* __restrict__ Ug,
    const float* __restrict__ Tg, float* __restrict__ outg,
    u64* __restrict__ ex)
{
  extern __shared__ float sm[];
  const int wg = blockIdx.x, tid = threadIdx.x;
  float* w1s = sm + OFF_W1;
  float* w2s = sm + OFF_W2;
  float* as_ = sm + OFF_A;
  float* bs_ = sm + OFF_B;
  float* cs_ = sm + OFF_C;
  float* b1s = sm + OFF_B1;
  float* b2s = sm + OFF_B2;
  float* zA  = sm + OFF_ZA;
  float* zB  = sm + OFF_ZB;
  float* hsh = sm + OFF_H;
  float* pts = sm + OFF_P;

  // ---- stage weights into LDS (once) ----
  for (int i = tid; i < N_W1; i += TPB) {
    int r = i / ZUN, k = i - r * ZUN;
    w1s[i] = W1g[(wg * W1R + r) * ZUN + k];
  }
  for (int i = tid; i < N_W2; i += TPB) {
    int c = i >> 8, r = i & (LN - 1);
    w2s[i] = W2g[r * HIDN + wg * W1R + c];   // transposed: w2s[c][r]
  }
  for (int i = tid; i < N_A; i += TPB) {
    int r = i >> 8, k = i & (LN - 1);
    as_[i] = Ag[(wg * GR + r) * LN + k];
  }
  for (int i = tid; i < N_B; i += TPB) {
    int m = i / (GR * LN); int rem = i - m * GR * LN;
    int r = rem >> 8, k = rem & (LN - 1);
    bs_[i] = Bg[(m * LN + wg * GR + r) * LN + k];
  }
  for (int i = tid; i < N_C; i += TPB) {
    int r = i >> 3, m = i & 7;
    cs_[i] = Cg[(wg * GR + r) * MM + m];
  }
  for (int i = tid; i < N_B1; i += TPB) b1s[i] = b1g[wg * W1R + i];
  for (int i = tid; i < N_B2; i += TPB) b2s[i] = b2g[wg * GR + i];

  float zb = 0.f, sb = 0.f, fb = 1.f, vb = 1.f, qb = 1.f;
  zA[tid] = 0.f;                            // initial z (stage-0 buffer)

  if (wg == 0) {                            // output row 0
    outg[tid] = 0.f;
    outg[LN + tid] = 0.f;
    outg[2 * LN + tid] = 1.f;
    outg[3 * LN + tid] = 1.f;
    outg[4 * LN + tid] = 1.f;
    outg[(size_t)2048 * 1280 + tid] = 0.f;
  }

  for (int t = 0; t < NSTEP; ++t) {
    float hstep = Tg[t + 1] - Tg[t];
    float zst = zb, sst = sb, fst = fb, vst = vb, qst = qb;
    float kz = 0.f, ks = 0.f, kf = 0.f, kv = 0.f, kq = 0.f;

    float u0r = 0.f, umr = 0.f, u1r = 0.f;
    if (tid < MM) {
      u0r = Ug[(2 * t) * MM + tid];
      umr = Ug[(2 * t + 1) * MM + tid];
      u1r = Ug[(2 * t + 2) * MM + tid];
    }

    for (int st = 0; st < 4; ++st) {
      const int stg = 4 * t + st;
      const unsigned e = (unsigned)stg + 1;
      float* zcur = (st & 1) ? zB : zA;
      float* znxt = (st & 1) ? zA : zB;
      u64* slot = ex + (size_t)(stg & 1) * (NWG * LN);

      if (tid < MM) zcur[LN + tid] = (st == 0) ? u0r : (st == 3) ? u1r : umr;
      __syncthreads();                      // (a) z (prev stage) + u visible

      float uu[MM];
      #pragma unroll
      for (int m = 0; m < MM; ++m) uu[m] = zcur[LN + m];

      // ---- phase 1: own 32 h rows = tanh(W1 @ zu + b1) ----
      {
        int row = tid >> 3, sub = tid & 7;
        const float* wrow = w1s + row * ZUN + sub * 33;
        const float* zrow = zcur + sub * 33;
        float acc = 0.f;
        #pragma unroll
        for (int j = 0; j < 33; ++j) acc += wrow[j] * zrow[j];
        acc += __shfl_xor(acc, 1);
        acc += __shfl_xor(acc, 2);
        acc += __shfl_xor(acc, 4);
        if (sub == 0) hsh[row] = tanhf(acc + b1s[row]);
      }
      // ---- phase 2: own 8 rows of (A + sum u_m B_m) z + Cu + alpha b2 ----
      {
        int grow = tid >> 5, gsub = tid & 31;
        const float* arow = as_ + grow * LN;
        float ga = 0.f;
        #pragma unroll
        for (int j = 0; j < 8; ++j) {
          int k = gsub + 32 * j;
          float w = arow[k];
          #pragma unroll
          for (int m = 0; m < MM; ++m) w += uu[m] * bs_[(m * GR + grow) * LN + k];
          ga += w * zcur[k];
        }
        ga += __shfl_xor(ga, 1);
        ga += __shfl_xor(ga, 2);
        ga += __shfl_xor(ga, 4);
        ga += __shfl_xor(ga, 8);
        ga += __shfl_xor(ga, 16);
        if (gsub == 0) {
          float cu = 0.f;
          #pragma unroll
          for (int m = 0; m < MM; ++m) cu += cs_[grow * MM + m] * uu[m];
          pts[grow] = ga + cu + ALPHA * b2s[grow];
        }
      }
      __syncthreads();                      // (b) hsh, pts visible

      // ---- phase 3: column-partial of alpha*W2@h + own exact rows ----
      float pr;
      {
        float a2 = 0.f;
        #pragma unroll 8
        for (int c = 0; c < W1R; ++c) a2 += w2s[c * LN + tid] * hsh[c];
        pr = ALPHA * a2;
        int rl = tid - wg * GR;
        if (rl >= 0 && rl < GR) pr += pts[rl];
      }
      // ---- publish fused word; proceed immediately (no drain, no flag) ----
      __hip_atomic_store(&slot[wg * LN + tid], fuse(e, pr),
                         __ATOMIC_RELAXED, __HIP_MEMORY_SCOPE_AGENT);

      // ---- hemodynamic elementwise (regs only; hides store flight) ----
      float ds = zst - KAPPA * sst - GAMMA * (fst - 1.f);
      float df = sst;
      float fv = exp2f(INV_HALPHA * log2f(vst));
      float dv = (fst - fv) / TAUC;
      float E  = 1.f - exp2f(LOG2_1MRHO / fst);
      float dq = (fst * E / RHOC - fv * qst / vst) / TAUC;

      // ---- speculative bulk poll: rounds of 32 independent 8B atomic loads ----
      u64 w[NWG];
      {
        int spins = 0;
        for (;;) {
          #pragma unroll
          for (int g = 0; g < NWG; ++g)
            w[g] = __hip_atomic_load(&slot[g * LN + tid],
                                     __ATOMIC_RELAXED, __HIP_MEMORY_SCOPE_AGENT);
          unsigned bad = 0u;
          #pragma unroll
          for (int g = 0; g < NWG; ++g)
            bad |= (unsigned)((unsigned)(w[g] >> 32) != e);
          if (!bad) break;
          if (++spins > DEADMAN) break;     // never in theory
        }
      }

      // ---- ordered reduction -> dz (bitwise-identical across WGs) ----
      float dz = 0.f;
      #pragma unroll
      for (int g = 0; g < NWG; ++g) dz += __uint_as_float((unsigned)w[g]);

      float wk = (st == 0 || st == 3) ? 1.f : 2.f;
      kz += wk * dz; ks += wk * ds; kf += wk * df; kv += wk * dv; kq += wk * dq;

      if (st < 3) {
        float c = (st == 2) ? hstep : 0.5f * hstep;
        zst = zb + c * dz; sst = sb + c * ds; fst = fb + c * df;
        vst = vb + c * dv; qst = qb + c * dq;
        znxt[tid] = zst;                    // other buffer: no reader conflict
      }
    }

    float h6 = hstep * (1.f / 6.f);
    zb += h6 * kz; sb += h6 * ks; fb += h6 * kf; vb += h6 * kv; qb += h6 * kq;
    zA[tid] = zb;                           // next step's stage-0 buffer

    if ((t & (NWG - 1)) == wg) {            // distribute output writes
      size_t ro = (size_t)(t + 1) * 1280;
      outg[ro + tid] = zb;
      outg[ro + LN + tid] = sb;
      outg[ro + 2 * LN + tid] = fb;
      outg[ro + 3 * LN + tid] = vb;
      outg[ro + 4 * LN + tid] = qb;
      float yv = V0C * (2.38f * (1.f - qb) + 2.f * (1.f - qb / vb) + 0.48f * (1.f - vb));
      outg[(size_t)2048 * 1280 + (size_t)(t + 1) * LN + tid] = yv;
    }
  }
}

extern "C" void kernel_launch(void* const* d_in, const int* in_sizes, int n_in,
                              void* d_out, int out_size, void* d_ws, size_t ws_size,
                              hipStream_t stream) {
  const float* Ag  = (const float*)d_in[0];
  const float* Bg  = (const float*)d_in[1];
  const float* Cg  = (const float*)d_in[2];
  const float* W1g = (const float*)d_in[3];
  const float* b1g = (const float*)d_in[4];
  const float* W2g = (const float*)d_in[5];
  const float* b2g = (const float*)d_in[6];
  const float* Ug  = (const float*)d_in[7];
  const float* Tg  = (const float*)d_in[8];
  float* outg = (float*)d_out;

  u64* ex = (u64*)d_ws;

  hipFuncSetAttribute((const void*)dcm_kernel,
                      hipFuncAttributeMaxDynamicSharedMemorySize, SMEM_BYTES);

  hipLaunchKernelGGL(dcm_kernel, dim3(NWG), dim3(TPB), SMEM_BYTES, stream,
                     Ag, Bg, Cg, W1g, b1g, W2g, b2g, Ug, Tg, outg, ex);
}

// Round 11
// 30462.119 us; speedup vs baseline: 1.6013x; 1.5513x over previous
//
#include <hip/hip_runtime.h>
#include <cmath>

#define LN 256
#define MM 8
#define HIDN 1024
#define NSTEP 2047
#define NWG 16
#define TPB 512
#define W1R 64       // W1 rows per WG (HID/NWG)
#define GR 16        // state rows per WG (L/NWG)
#define ZUP 272      // zu padded (264 real + 8 zero-pad)

#define KAPPA 0.65f
#define GAMMA 0.41f
#define TAUC 0.98f
#define INV_HALPHA 3.125f
#define RHOC 0.34f
#define V0C 0.04f
#define ALPHA 0.1f
#define LOG2_1MRHO (-0.5994620717f)

#define DEADMAN (1<<14)

// ---- LDS byte offsets ----
#define OB_W1 0                       // uint[64*136]  W1 bf16 pairs, row stride 136 uints
#define OB_W2 34816                   // uint[32*256]  W2 col-pairs: [cc][r]
#define OB_A  67584                   // float[16*256]
#define OB_B  83968                   // uint4[16*256] B bf16 pairs [grow][k][m0..7]
#define OB_C  150016                  // float[16*8]
#define OB_B1 150528                  // float[64]
#define OB_B2 150784                  // float[16]
#define OB_ZA 150848                  // float[272]
#define OB_ZB 151936                  // float[272]
#define OB_H  153024                  // float[64]
#define OB_P  153280                  // float[16]
#define SMEM_BYTES 153344

// d_ws: flags[16] u32 @64B stride (1 KB) ; part[2][16][256] float @4096 (32 KB)
#define WS_PART_OFF 4096
#define FSTR 16

typedef unsigned int uint;

__global__ void dcm_init(uint* flags) {
  if (threadIdx.x < NWG * FSTR) flags[threadIdx.x] = 0u;
}

__device__ __forceinline__ unsigned short f2b(float f) {
  uint u = __float_as_uint(f);
  return (unsigned short)((u + 0x7FFFu + ((u >> 16) & 1u)) >> 16);  // RNE
}
__device__ __forceinline__ uint packb(float lo, float hi) {
  return (uint)f2b(lo) | ((uint)f2b(hi) << 16);
}
__device__ __forceinline__ float blo(uint u) { return __uint_as_float(u << 16); }
__device__ __forceinline__ float bhi(uint u) { return __uint_as_float(u & 0xFFFF0000u); }

__global__ void __launch_bounds__(TPB, 1) dcm_kernel(
    const float* __restrict__ Ag, const float* __restrict__ Bg,
    const float* __restrict__ Cg, const float* __restrict__ W1g,
    const float* __restrict__ b1g, const float* __restrict__ W2g,
    const float* __restrict__ b2g, const float* __restrict__ Ug,
    const float* __restrict__ Tg, float* __restrict__ outg,
    float* __restrict__ part, uint* __restrict__ flags)
{
  extern __shared__ char smraw[];
  const int wg = blockIdx.x, tid = threadIdx.x;
  uint*  w1u = (uint*)(smraw + OB_W1);
  uint*  w2u = (uint*)(smraw + OB_W2);
  float* as_ = (float*)(smraw + OB_A);
  uint4* bu  = (uint4*)(smraw + OB_B);
  float* cs_ = (float*)(smraw + OB_C);
  float* b1s = (float*)(smraw + OB_B1);
  float* b2s = (float*)(smraw + OB_B2);
  float* zA  = (float*)(smraw + OB_ZA);
  float* zB  = (float*)(smraw + OB_ZB);
  float* hsh = (float*)(smraw + OB_H);
  float* pts = (float*)(smraw + OB_P);

  // ---- stage weights into LDS (once) ----
  for (int i = tid; i < W1R * 136; i += TPB) {          // W1 bf16 pairs (+zero pad)
    int r = i / 136, jd = i - r * 136, k = 2 * jd;
    const float* src = W1g + (size_t)(wg * W1R + r) * 264;
    float lo = (k < 264) ? src[k] : 0.f;
    float hi = (k + 1 < 264) ? src[k + 1] : 0.f;
    w1u[i] = packb(lo, hi);
  }
  for (int i = tid; i < 32 * 256; i += TPB) {           // W2 column pairs [cc][r]
    int cc = i >> 8, r = i & 255;
    const float* src = W2g + (size_t)r * HIDN + wg * W1R + 2 * cc;
    w2u[i] = packb(src[0], src[1]);
  }
  for (int i = tid; i < GR * 256; i += TPB) {           // A fp32
    int r = i >> 8, k = i & 255;
    as_[i] = Ag[(size_t)(wg * GR + r) * 256 + k];
  }
  {                                                     // B bf16 pairs [grow][k][m]
    uint* bw = (uint*)bu;
    for (int i = tid; i < GR * 256 * 4; i += TPB) {
      int grow = i >> 10, rem = i & 1023, k = rem >> 2, um = rem & 3, m = 2 * um;
      int gi = wg * GR + grow;
      float lo = Bg[((size_t)m * 256 + gi) * 256 + k];
      float hi = Bg[((size_t)(m + 1) * 256 + gi) * 256 + k];
      bw[(grow * 256 + k) * 4 + um] = packb(lo, hi);
    }
  }
  for (int i = tid; i < GR * MM; i += TPB) {
    int r = i >> 3, m = i & 7;
    cs_[i] = Cg[(wg * GR + r) * MM + m];
  }
  for (int i = tid; i < W1R; i += TPB) b1s[i] = b1g[wg * W1R + i];
  for (int i = tid; i < GR; i += TPB)  b2s[i] = b2g[wg * GR + i];

  float zb = 0.f, sb = 0.f, fb = 1.f, vb = 1.f, qb = 1.f;
  if (tid < LN) { zA[tid] = 0.f; }
  if (tid >= LN && tid < LN + (ZUP - 264)) {            // zero the pads once (both buffers)
    zA[264 + (tid - LN)] = 0.f; zB[264 + (tid - LN)] = 0.f;
  }

  if (wg == 0 && tid < LN) {                            // output row 0
    outg[tid] = 0.f;
    outg[LN + tid] = 0.f;
    outg[2 * LN + tid] = 1.f;
    outg[3 * LN + tid] = 1.f;
    outg[4 * LN + tid] = 1.f;
    outg[(size_t)2048 * 1280 + tid] = 0.f;
  }

  for (int t = 0; t < NSTEP; ++t) {
    float hstep = Tg[t + 1] - Tg[t];
    float zst = zb, sst = sb, fst = fb, vst = vb, qst = qb;
    float kz = 0.f, ks = 0.f, kf = 0.f, kv = 0.f, kq = 0.f;

    float u0r = 0.f, umr = 0.f, u1r = 0.f;
    if (tid < MM) {
      u0r = Ug[(2 * t) * MM + tid];
      umr = Ug[(2 * t + 1) * MM + tid];
      u1r = Ug[(2 * t + 2) * MM + tid];
    }

    for (int st = 0; st < 4; ++st) {
      const int stg = 4 * t + st;
      const uint fl = (uint)stg + 1;
      float* zcur = (st & 1) ? zB : zA;
      float* znxt = (st & 1) ? zA : zB;
      float* pslot = part + (size_t)(stg & 1) * (NWG * LN);

      if (tid < MM) zcur[LN + tid] = (st == 0) ? u0r : (st == 3) ? u1r : umr;
      __syncthreads();                      // (a) z + u visible

      float uu[MM];
      #pragma unroll
      for (int m = 0; m < MM; ++m) uu[m] = zcur[LN + m];

      // ---- phase 1: 64 h rows, 8 lanes/row, bf16 pair MACs ----
      {
        int row = tid >> 3, sub = tid & 7;
        const uint* wrow = w1u + row * 136 + sub * 17;
        const float* zp = zcur + sub * 34;
        float acc = 0.f;
        #pragma unroll
        for (int j = 0; j < 17; ++j) {
          uint u = wrow[j];
          acc += blo(u) * zp[2 * j];
          acc += bhi(u) * zp[2 * j + 1];
        }
        acc += __shfl_xor(acc, 1);
        acc += __shfl_xor(acc, 2);
        acc += __shfl_xor(acc, 4);
        if (sub == 0) hsh[row] = tanhf(acc + b1s[row]);
      }
      // ---- phase 2: 16 dz-rows of A,B,C part; 32 lanes/row ----
      {
        int grow = tid >> 5, gsub = tid & 31;
        const float* arow = as_ + grow * 256;
        const uint4* bp = bu + grow * 256;
        float ga = 0.f;
        #pragma unroll
        for (int j = 0; j < 8; ++j) {
          int k = gsub + 32 * j;
          uint4 b = bp[k];
          float w = arow[k];
          w += blo(b.x) * uu[0] + bhi(b.x) * uu[1];
          w += blo(b.y) * uu[2] + bhi(b.y) * uu[3];
          w += blo(b.z) * uu[4] + bhi(b.z) * uu[5];
          w += blo(b.w) * uu[6] + bhi(b.w) * uu[7];
          ga += w * zcur[k];
        }
        ga += __shfl_xor(ga, 1);
        ga += __shfl_xor(ga, 2);
        ga += __shfl_xor(ga, 4);
        ga += __shfl_xor(ga, 8);
        ga += __shfl_xor(ga, 16);
        if (gsub == 0) {
          float cu = 0.f;
          #pragma unroll
          for (int m = 0; m < MM; ++m) cu += cs_[grow * MM + m] * uu[m];
          pts[grow] = ga + cu + ALPHA * b2s[grow];
        }
      }
      __syncthreads();                      // (b) hsh, pts visible

      float ds = 0.f, df = 0.f, dv = 0.f, dq = 0.f;
      if (tid < LN) {
        // ---- phase 3: column-partial alpha*W2@h + own exact rows; store ----
        float acc = 0.f;
        const uint* wp = w2u + tid;
        #pragma unroll
        for (int cc = 0; cc < 32; ++cc) {
          uint u = wp[cc * 256];
          acc += blo(u) * hsh[2 * cc];
          acc += bhi(u) * hsh[2 * cc + 1];
        }
        float pr = ALPHA * acc;
        int rl = tid - wg * GR;
        if (rl >= 0 && rl < GR) pr += pts[rl];
        __hip_atomic_store(&pslot[wg * LN + tid], pr,
                           __ATOMIC_RELAXED, __HIP_MEMORY_SCOPE_AGENT);

        // ---- hemodynamics (regs; hides store flight) ----
        ds = zst - KAPPA * sst - GAMMA * (fst - 1.f);
        df = sst;
        float fvp = exp2f(INV_HALPHA * log2f(vst));
        dv = (fst - fvp) / TAUC;
        float E = 1.f - exp2f(LOG2_1MRHO / fst);
        dq = (fst * E / RHOC - fvp * qst / vst) / TAUC;
      }

      __syncthreads();                      // (drain) all waves' stores acked

      if (tid == 0)
        __hip_atomic_store(&flags[wg * FSTR], fl,
                           __ATOMIC_RELAXED, __HIP_MEMORY_SCOPE_AGENT);

      if (tid < LN) {
        // ---- poll 16 flags (lanes map l&15; 2 samples per round) ----
        {
          const uint* fp_ = &flags[((tid & 63) & 15) * FSTR];
          int spins = 0;
          for (;;) {
            uint v0 = __hip_atomic_load(fp_, __ATOMIC_RELAXED, __HIP_MEMORY_SCOPE_AGENT);
            if (__ballot(v0 >= fl) == 0xFFFFFFFFFFFFFFFFull) break;
            uint v1 = __hip_atomic_load(fp_, __ATOMIC_RELAXED, __HIP_MEMORY_SCOPE_AGENT);
            if (__ballot(v1 >= fl) == 0xFFFFFFFFFFFFFFFFull) break;
            if (++spins > DEADMAN) break;   // never in theory
          }
        }
        // ---- wide gather: 16 loads, ordered sum ----
        float arr[NWG];
        #pragma unroll
        for (int g = 0; g < NWG; ++g)
          arr[g] = __hip_atomic_load(&pslot[g * LN + tid],
                                     __ATOMIC_RELAXED, __HIP_MEMORY_SCOPE_AGENT);
        float dz = 0.f;
        #pragma unroll
        for (int g = 0; g < NWG; ++g) dz += arr[g];

        float wk = (st == 0 || st == 3) ? 1.f : 2.f;
        kz += wk * dz; ks += wk * ds; kf += wk * df; kv += wk * dv; kq += wk * dq;

        if (st < 3) {
          float c = (st == 2) ? hstep : 0.5f * hstep;
          zst = zb + c * dz; sst = sb + c * ds; fst = fb + c * df;
          vst = vb + c * dv; qst = qb + c * dq;
          znxt[tid] = zst;                  // other buffer: no reader conflict
        }
      }
    }

    if (tid < LN) {
      float h6 = hstep * (1.f / 6.f);
      zb += h6 * kz; sb += h6 * ks; fb += h6 * kf; vb += h6 * kv; qb += h6 * kq;
      zA[tid] = zb;                         // next step's stage-0 buffer

      if ((t & (NWG - 1)) == wg) {          // distribute output writes
        size_t ro = (size_t)(t + 1) * 1280;
        outg[ro + tid] = zb;
        outg[ro + LN + tid] = sb;
        outg[ro + 2 * LN + tid] = fb;
        outg[ro + 3 * LN + tid] = vb;
        outg[ro + 4 * LN + tid] = qb;
        float yv = V0C * (2.38f * (1.f - qb) + 2.f * (1.f - qb / vb) + 0.48f * (1.f - vb));
        outg[(size_t)2048 * 1280 + (size_t)(t + 1) * LN + tid] = yv;
      }
    }
  }
}

extern "C" void kernel_launch(void* const* d_in, const int* in_sizes, int n_in,
                              void* d_out, int out_size, void* d_ws, size_t ws_size,
                              hipStream_t stream) {
  const float* Ag  = (const float*)d_in[0];
  const float* Bg  = (const float*)d_in[1];
  const float* Cg  = (const float*)d_in[2];
  const float* W1g = (const float*)d_in[3];
  const float* b1g = (const float*)d_in[4];
  const float* W2g = (const float*)d_in[5];
  const float* b2g = (const float*)d_in[6];
  const float* Ug  = (const float*)d_in[7];
  const float* Tg  = (const float*)d_in[8];
  float* outg = (float*)d_out;

  uint* flags = (uint*)d_ws;
  float* part = (float*)((char*)d_ws + WS_PART_OFF);

  hipFuncSetAttribute((const void*)dcm_kernel,
                      hipFuncAttributeMaxDynamicSharedMemorySize, SMEM_BYTES);

  hipLaunchKernelGGL(dcm_init, dim3(1), dim3(256), 0, stream, flags);
  hipLaunchKernelGGL(dcm_kernel, dim3(NWG), dim3(TPB), SMEM_BYTES, stream,
                     Ag, Bg, Cg, W1g, b1g, W2g, b2g, Ug, Tg, outg, part, flags);
}